// Round 6
// baseline (31406.775 us; speedup 1.0000x reference)
//
#include <hip/hip_runtime.h>
#include <cstddef>

// Decoder: B=64, T=512, I=512, H1=256, H2=128, C=1024, M=80, L=2
// Round 6: single persistent kernel for all 512 timesteps. 256 blocks x 512
// threads (1 block/CU). 4 phases/step separated by a custom gen-barrier
// (release arrivals + relaxed spin -> no L2 invalidate, weights stay L2
// resident). Cross-block activations via relaxed agent-scope atomics (sc1,
// MALL-coherent). Phase bodies identical math to R5 (passed, absmax 0.0039).

namespace {

constexpr int kB = 64, kT = 512, kI = 512, kH1 = 256, kH2 = 128, kC = 1024, kM = 80;

typedef __attribute__((ext_vector_type(8))) __bf16 bf16x8;
typedef __attribute__((ext_vector_type(4))) float f32x4;

__device__ __forceinline__ float sigm(float x) { return 1.0f / (1.0f + __expf(-x)); }
__device__ __forceinline__ float tanh_(float x) {
  float a = fabsf(x);
  float e = __expf(-2.0f * a);
  float r = (1.0f - e) / (1.0f + e);
  return copysignf(r, x);
}
__device__ __forceinline__ unsigned short f2bf(float x) {
  unsigned u = __builtin_bit_cast(unsigned, x);
  u += 0x7fffu + ((u >> 16) & 1u);   // RNE
  return (unsigned short)(u >> 16);
}
__device__ __forceinline__ bf16x8 asbf(uint4 v) { return __builtin_bit_cast(bf16x8, v); }
__device__ __forceinline__ f32x4 mfma16(bf16x8 a, bf16x8 b, f32x4 c) {
  return __builtin_amdgcn_mfma_f32_16x16x32_bf16(a, b, c, 0, 0, 0);
}

// ---- agent-scope (cross-XCD coherent) relaxed accessors --------------------
__device__ __forceinline__ float ld_f(const float* p) {
  return __hip_atomic_load(p, __ATOMIC_RELAXED, __HIP_MEMORY_SCOPE_AGENT);
}
__device__ __forceinline__ void st_f(float* p, float v) {
  __hip_atomic_store(p, v, __ATOMIC_RELAXED, __HIP_MEMORY_SCOPE_AGENT);
}
__device__ __forceinline__ unsigned long long ld_u64(const unsigned long long* p) {
  return __hip_atomic_load(p, __ATOMIC_RELAXED, __HIP_MEMORY_SCOPE_AGENT);
}
__device__ __forceinline__ void st_u32(unsigned* p, unsigned v) {
  __hip_atomic_store(p, v, __ATOMIC_RELAXED, __HIP_MEMORY_SCOPE_AGENT);
}
__device__ __forceinline__ void st_u16(unsigned short* p, unsigned short v) {
  __hip_atomic_store(p, v, __ATOMIC_RELAXED, __HIP_MEMORY_SCOPE_AGENT);
}

// ---- weight repack: fp32 [row][col] -> bf16 frag order [rt][ks][lane][8] ----
__global__ __launch_bounds__(256) void k_build_frags(
    const float* __restrict__ srcA, int ldA,
    const float* __restrict__ srcB, int ldB,
    int row0, int K1, int nks, int nrt, unsigned short* __restrict__ dst) {
  int idx = blockIdx.x * 256 + threadIdx.x;
  int lane = idx & 63;
  int ks = (idx >> 6) % nks;
  int rt = idx / (64 * nks);
  if (rt >= nrt) return;
  int row = row0 + rt * 16 + (lane & 15);
  int kk = ks * 32 + ((lane >> 4) & 3) * 8;
  const float* s = (kk < K1) ? (srcA + (size_t)row * ldA + kk)
                             : (srcB + (size_t)row * ldB + (kk - K1));
  unsigned short* d = dst + ((size_t)(rt * nks + ks) * 64 + lane) * 8;
#pragma unroll
  for (int j = 0; j < 8; ++j) d[j] = f2bf(s[j]);
}

__global__ __launch_bounds__(256) void k_transpose(const float* __restrict__ src,
    int R, int Ccols, float* __restrict__ dst) {
  int i = blockIdx.x * 256 + threadIdx.x;
  if (i >= R * Ccols) return;
  int r = i / Ccols, c = i % Ccols;
  dst[c * R + r] = src[r * Ccols + c];
}

// ---- persistent kernel params ----------------------------------------------
struct P {
  const float* inputs;
  const float* w0t; const float* pre_b0;
  const float* w1t; const float* pre_b1;
  const unsigned short* Aa0; const unsigned short* Aa1; const unsigned short* Aa2;
  const float* attn_bih; const float* attn_bhh;
  const unsigned short* A10; const unsigned short* A11; const unsigned short* A12;
  const unsigned short* A20; const unsigned short* A21; const unsigned short* A22;
  const float* gru_bih; const float* gru_bhh;     // layer0; layer1 at +3C
  const float* proj_w; const float* proj_b;
  unsigned short* xcat0; unsigned short* xcat1; unsigned short* xcat2;
  float* hA; float* h1; float* h2; float* x1; float* pproj;
  float* out;
  unsigned* bar_cnt; unsigned* bar_gen;
};

__device__ __forceinline__ void gridbar(unsigned* cnt, unsigned* gen, unsigned& g) {
  __syncthreads();
  if (threadIdx.x == 0) {
    unsigned a = __hip_atomic_fetch_add(cnt, 1u, __ATOMIC_RELEASE, __HIP_MEMORY_SCOPE_AGENT);
    if (a == 255u) {
      __hip_atomic_store(cnt, 0u, __ATOMIC_RELAXED, __HIP_MEMORY_SCOPE_AGENT);
      __hip_atomic_store(gen, g + 1u, __ATOMIC_RELEASE, __HIP_MEMORY_SCOPE_AGENT);
    } else {
      while (__hip_atomic_load(gen, __ATOMIC_RELAXED, __HIP_MEMORY_SCOPE_AGENT) == g) {}
    }
  }
  __syncthreads();
  g += 1u;
}

// ---- prenet phase (blocks with bt==0; b = rt); all 512 threads enter --------
__device__ __forceinline__ void prenet_phase(const P& p, int b, int t,
    unsigned short* xc0cur, float* sfr, float* sh, float* sred) {
  int tid = threadIdx.x;
  unsigned short* dst = xc0cur + (size_t)b * 1664;
  if (tid < 256) {
    const float* feat = p.inputs + ((size_t)b * kT + t) * kI;
    float2 f2v = *(const float2*)(feat + tid * 2);
    unsigned pack = (unsigned)f2bf(f2v.x) | ((unsigned)f2bf(f2v.y) << 16);
    st_u32((unsigned*)dst + tid, pack);
  }
  if (t > 0) {
    if (tid < 160) {
      int m = tid >> 1, half = tid & 1;
      const float* pp = p.pproj + ((size_t)(half * 32) * kM + m) * kB + b;
      float s = 0.0f;
#pragma unroll 8
      for (int r = 0; r < 32; ++r) s += ld_f(pp + (size_t)r * kM * kB);
      sred[tid] = s;
    }
    __syncthreads();
    if (tid < kM) {
      float f = p.proj_b[tid] + sred[tid * 2] + sred[tid * 2 + 1];
      sfr[tid] = f;
      p.out[(size_t)b * kT * kM + (size_t)(t - 1) * kM + tid] = f;
    }
  } else {
    if (tid < kM) sfr[tid] = 0.0f;
  }
  __syncthreads();
  if (tid < 256) {
    float acc = p.pre_b0[tid];
#pragma unroll 8
    for (int m = 0; m < kM; ++m) acc = fmaf(p.w0t[m * kH1 + tid], sfr[m], acc);
    sh[tid] = fmaxf(acc, 0.0f);
  }
  __syncthreads();
  if (tid < kH2) {
    float a = p.pre_b1[tid];
#pragma unroll 8
    for (int k = 0; k < kH1; ++k) a = fmaf(p.w1t[k * kH2 + tid], sh[k], a);
    st_u16(dst + 512 + tid, f2bf(fmaxf(a, 0.0f)));
  }
}

// ---- GRU phase (R5-verified math; B via agent atomics) ----------------------
template<int NKS, int NB, int BROW>
__device__ __forceinline__ void gru_phase(int rt, int bt,
    const unsigned short* Ar, const unsigned short* Az, const unsigned short* An,
    const unsigned short* Bsrc, const float* h_old,
    const float* bih, const float* bhh, const float* xin_f32,
    float* h_new_f32, unsigned short* h_bf16, int hStride, int hOff,
    unsigned short* x_bf16, int xStride, float* xout_f32,
    const float* pw, float* pproj, float* red, float* sx) {
  int tid = threadIdx.x, lane = tid & 63, w = tid >> 6, quad = lane >> 4;
  int b = bt * 16 + (lane & 15);
  int s = (w * NKS) >> 3, e = ((w + 1) * NKS) >> 3;
  const unsigned long long* B8 =
      (const unsigned long long*)Bsrc + ((size_t)b * BROW + quad) * 2;
  const uint4* Arq = (const uint4*)Ar + (size_t)rt * NKS * 64 + lane;
  const uint4* Azq = (const uint4*)Az + (size_t)rt * NKS * 64 + lane;
  const uint4* Anq = (const uint4*)An + (size_t)rt * NKS * 64 + lane;
  f32x4 aR = {0.f, 0.f, 0.f, 0.f}, aZ = aR, aNI = aR, aNH = aR;
  for (int ks = s; ks < e; ++ks) {
    union { unsigned long long q[2]; bf16x8 v; } u;
    u.q[0] = ld_u64(B8 + (size_t)ks * 8);
    u.q[1] = ld_u64(B8 + (size_t)ks * 8 + 1);
    aR = mfma16(asbf(Arq[ks * 64]), u.v, aR);
    aZ = mfma16(asbf(Azq[ks * 64]), u.v, aZ);
    if (ks < NB) aNI = mfma16(asbf(Anq[ks * 64]), u.v, aNI);
    else         aNH = mfma16(asbf(Anq[ks * 64]), u.v, aNH);
  }
  *(f32x4*)(red + ((w * 4 + 0) * 64 + lane) * 4) = aR;
  *(f32x4*)(red + ((w * 4 + 1) * 64 + lane) * 4) = aZ;
  *(f32x4*)(red + ((w * 4 + 2) * 64 + lane) * 4) = aNI;
  *(f32x4*)(red + ((w * 4 + 3) * 64 + lane) * 4) = aNH;
  __syncthreads();
  if (w < 4) {
    int q = lane >> 4, bb = lane & 15;
    int b2 = bt * 16 + bb;
    float R = 0.f, Z = 0.f, NI = 0.f, NH = 0.f;
#pragma unroll
    for (int ww = 0; ww < 8; ++ww) {
      int base = (ww * 4 * 64 + w * 16 + bb) * 4 + q;
      R  += red[base];
      Z  += red[base + 64 * 4];
      NI += red[base + 2 * 64 * 4];
      NH += red[base + 3 * 64 * 4];
    }
    int c = rt * 16 + w * 4 + q;
    float r = sigm(R + bih[c] + bhh[c]);
    float z = sigm(Z + bih[kC + c] + bhh[kC + c]);
    float n = tanh_(NI + bih[2 * kC + c] + r * (NH + bhh[2 * kC + c]));
    float hold = ld_f(h_old + c * kB + b2);
    float hn = (1.0f - z) * n + z * hold;
    st_f(h_new_f32 + c * kB + b2, hn);
    st_u16(h_bf16 + (size_t)b2 * hStride + hOff + c, f2bf(hn));
    float xo = xin_f32 ? (ld_f(xin_f32 + c * kB + b2) + hn) : hn;
    if (x_bf16) st_u16(x_bf16 + (size_t)b2 * xStride + c, f2bf(xo));
    if (xout_f32) st_f(xout_f32 + c * kB + b2, xo);
    if (pw) sx[(w * 4 + q) * 16 + bb] = xo;   // [c16][b16]
  }
  if (pw) {
    __syncthreads();
    for (int idx = tid; idx < kM * 16; idx += 512) {
      int m = idx >> 4, bb = idx & 15;
      const float* wrow = pw + (size_t)m * kC + rt * 16;
      float a = 0.f;
#pragma unroll
      for (int c16 = 0; c16 < 16; ++c16) a += wrow[c16] * sx[c16 * 16 + bb];
      st_f(pproj + ((size_t)rt * kM + m) * kB + bt * 16 + bb, a);
    }
  }
}

// ---- the persistent decoder kernel -----------------------------------------
__global__ __launch_bounds__(512, 2) void k_decoder(P p) {
  __shared__ float red[8192];   // 32 KB, shared across phases
  __shared__ float sx[256];
  int xcd = blockIdx.x & 7, slot = blockIdx.x >> 3;
  int rt = xcd * 8 + (slot >> 2);   // each XCD owns 8 complete row-tiles
  int bt = slot & 3;
  unsigned g = 0;
  const size_t X0 = (size_t)kB * 1664;
  const size_t XC = (size_t)kB * 2048;
  const size_t HB = (size_t)kC * kB;
  const float* g_bih1 = p.gru_bih + 3 * kC;
  const float* g_bhh1 = p.gru_bhh + 3 * kC;

  for (int t = 0; t < kT; ++t) {
    int cur = t & 1, nxt = cur ^ 1;
    // P0: prenet (+frame t-1 reduce/write); 64 blocks active
    if (bt == 0)
      prenet_phase(p, rt, t, p.xcat0 + cur * X0, red, red + 128, red + 512);
    gridbar(p.bar_cnt, p.bar_gen, g);
    // P1: attention GRU
    gru_phase<52, 20, 208>(rt, bt, p.Aa0, p.Aa1, p.Aa2,
        p.xcat0 + cur * X0, p.hA + cur * HB, p.attn_bih, p.attn_bhh, nullptr,
        p.hA + nxt * HB, p.xcat0 + nxt * X0, 1664, 640,
        p.xcat1 + cur * XC, 2048, nullptr, nullptr, nullptr, red, sx);
    gridbar(p.bar_cnt, p.bar_gen, g);
    // P2: residual GRU 1
    gru_phase<64, 32, 256>(rt, bt, p.A10, p.A11, p.A12,
        p.xcat1 + cur * XC, p.h1 + cur * HB, p.gru_bih, p.gru_bhh,
        p.hA + nxt * HB,
        p.h1 + nxt * HB, p.xcat1 + nxt * XC, 2048, 1024,
        p.xcat2 + cur * XC, 2048, p.x1, nullptr, nullptr, red, sx);
    gridbar(p.bar_cnt, p.bar_gen, g);
    // P3: residual GRU 2 + proj partials
    gru_phase<64, 32, 256>(rt, bt, p.A20, p.A21, p.A22,
        p.xcat2 + cur * XC, p.h2 + cur * HB, g_bih1, g_bhh1,
        p.x1,
        p.h2 + nxt * HB, p.xcat2 + nxt * XC, 2048, 1024,
        nullptr, 0, nullptr, p.proj_w, p.pproj, red, sx);
    gridbar(p.bar_cnt, p.bar_gen, g);
  }
  // final frame t = 511
  if (bt == 0 && threadIdx.x < kM) {
    int m = threadIdx.x;
    float s = p.proj_b[m];
#pragma unroll 8
    for (int r = 0; r < 64; ++r)
      s += ld_f(p.pproj + ((size_t)r * kM + m) * kB + rt);
    p.out[((size_t)rt * kT + (kT - 1)) * kM + m] = s;
  }
}

} // namespace

extern "C" void kernel_launch(void* const* d_in, const int* in_sizes, int n_in,
                              void* d_out, int out_size, void* d_ws, size_t ws_size,
                              hipStream_t stream) {
  const float* inputs   = (const float*)d_in[0];
  const float* pre_w0   = (const float*)d_in[1];
  const float* pre_b0   = (const float*)d_in[2];
  const float* pre_w1   = (const float*)d_in[3];
  const float* pre_b1   = (const float*)d_in[4];
  const float* attn_wih = (const float*)d_in[5];
  const float* attn_whh = (const float*)d_in[6];
  const float* attn_bih = (const float*)d_in[7];
  const float* attn_bhh = (const float*)d_in[8];
  const float* gru_wih  = (const float*)d_in[9];
  const float* gru_whh  = (const float*)d_in[10];
  const float* gru_bih  = (const float*)d_in[11];
  const float* gru_bhh  = (const float*)d_in[12];
  const float* proj_w   = (const float*)d_in[13];
  const float* proj_b   = (const float*)d_in[14];
  float* out = (float*)d_out;
  char* ws = (char*)d_ws;

  const size_t ATTN_MAT = (size_t)64 * 52 * 64 * 8 * 2;  // 3,407,872 B
  const size_t RES_MAT  = (size_t)64 * 64 * 64 * 8 * 2;  // 4,194,304 B
  size_t off = 0;
  unsigned short* Aattn[3];
  for (int g = 0; g < 3; ++g) { Aattn[g] = (unsigned short*)(ws + off); off += ATTN_MAT; }
  unsigned short* Ares[2][3];
  for (int l = 0; l < 2; ++l)
    for (int g = 0; g < 3; ++g) { Ares[l][g] = (unsigned short*)(ws + off); off += RES_MAT; }
  float* w0t = (float*)(ws + off); off += (size_t)kM * kH1 * 4;
  float* w1t = (float*)(ws + off); off += (size_t)kH1 * kH2 * 4;
  float* pproj = (float*)(ws + off); off += (size_t)64 * kM * kB * 4;    // 1.25 MB
  size_t zeroBase = off;
  unsigned* bar_cnt = (unsigned*)(ws + off); off += 128;
  unsigned* bar_gen = (unsigned*)(ws + off); off += 128;
  unsigned short* xcat0 = (unsigned short*)(ws + off); off += 2 * (size_t)kB * 1664 * 2;
  unsigned short* xcat1 = (unsigned short*)(ws + off); off += 2 * (size_t)kB * 2048 * 2;
  unsigned short* xcat2 = (unsigned short*)(ws + off); off += 2 * (size_t)kB * 2048 * 2;
  const size_t HB = (size_t)kC * kB;
  float* hA = (float*)(ws + off); off += 2 * HB * 4;
  float* h1 = (float*)(ws + off); off += 2 * HB * 4;
  float* h2 = (float*)(ws + off); off += 2 * HB * 4;
  float* x1 = (float*)(ws + off); off += HB * 4;
  if (off > ws_size) return;  // fail loud if workspace too small

  // ---- one-time per launch: weight repack + transposes + zero init ----
  for (int g = 0; g < 3; ++g)
    k_build_frags<<<16 * 52, 256, 0, stream>>>(attn_wih, 640, attn_whh, kC,
                                               g * kC, 640, 52, 64, Aattn[g]);
  for (int l = 0; l < 2; ++l) {
    const float* wih = gru_wih + (size_t)l * 3 * kC * kC;
    const float* whh = gru_whh + (size_t)l * 3 * kC * kC;
    for (int g = 0; g < 3; ++g)
      k_build_frags<<<16 * 64, 256, 0, stream>>>(wih, kC, whh, kC,
                                                 g * kC, kC, 64, 64, Ares[l][g]);
  }
  k_transpose<<<(kH1 * kM + 255) / 256, 256, 0, stream>>>(pre_w0, kH1, kM, w0t);
  k_transpose<<<(kH2 * kH1 + 255) / 256, 256, 0, stream>>>(pre_w1, kH2, kH1, w1t);
  hipMemsetAsync(ws + zeroBase, 0, off - zeroBase, stream);

  P p;
  p.inputs = inputs;
  p.w0t = w0t; p.pre_b0 = pre_b0; p.w1t = w1t; p.pre_b1 = pre_b1;
  p.Aa0 = Aattn[0]; p.Aa1 = Aattn[1]; p.Aa2 = Aattn[2];
  p.attn_bih = attn_bih; p.attn_bhh = attn_bhh;
  p.A10 = Ares[0][0]; p.A11 = Ares[0][1]; p.A12 = Ares[0][2];
  p.A20 = Ares[1][0]; p.A21 = Ares[1][1]; p.A22 = Ares[1][2];
  p.gru_bih = gru_bih; p.gru_bhh = gru_bhh;
  p.proj_w = proj_w; p.proj_b = proj_b;
  p.xcat0 = xcat0; p.xcat1 = xcat1; p.xcat2 = xcat2;
  p.hA = hA; p.h1 = h1; p.h2 = h2; p.x1 = x1; p.pproj = pproj;
  p.out = out;
  p.bar_cnt = bar_cnt; p.bar_gen = bar_gen;

  k_decoder<<<256, 512, 0, stream>>>(p);
}